// Round 1
// baseline (1650.100 us; speedup 1.0000x reference)
//
#include <hip/hip_runtime.h>
#include <hip/hip_bf16.h>

typedef unsigned short u16;
typedef __attribute__((ext_vector_type(4))) float f32x4;
typedef __attribute__((ext_vector_type(8))) short s16x8;
typedef __attribute__((ext_vector_type(4))) unsigned int u32x4;
typedef __attribute__((ext_vector_type(4))) u16 u16x4;
typedef __attribute__((ext_vector_type(8))) u16 u16x8;

static __device__ __forceinline__ u16 f2bf(float f) {
  __hip_bfloat16 b = __float2bfloat16(f);
  u16 u; __builtin_memcpy(&u, &b, 2); return u;
}
static __device__ __forceinline__ float bf2f(u16 u) {
  unsigned int v = ((unsigned int)u) << 16;
  float f; __builtin_memcpy(&f, &v, 4); return f;
}

// ---------------- elementwise f32 -> bf16 convert ----------------
__global__ __launch_bounds__(256) void cvt_f32_bf16(const float* __restrict__ src,
                                                    u16* __restrict__ dst, int n4) {
  int i = blockIdx.x * 256 + threadIdx.x;
  if (i < n4) {
    f32x4 v = ((const f32x4*)src)[i];
    u16x4 o;
    o[0] = f2bf(v[0]); o[1] = f2bf(v[1]); o[2] = f2bf(v[2]); o[3] = f2bf(v[3]);
    ((u16x4*)dst)[i] = o;
  }
}

// ---------------- tiled transpose + convert: src (R,X) f32 -> dst (X,R) bf16 ----------------
__global__ __launch_bounds__(256) void transpose_cvt(const float* __restrict__ src,
                                                     u16* __restrict__ dst,
                                                     int R, int X, long sB, long dB) {
  src += (long)blockIdx.z * sB;
  dst += (long)blockIdx.z * dB;
  int x0 = blockIdx.x * 64, r0 = blockIdx.y * 64;
  __shared__ float t[64][65];
  int tid = threadIdx.x;
#pragma unroll
  for (int rep = 0; rep < 4; ++rep) {
    int u = tid + rep * 256;
    int r = u >> 4, xq = (u & 15) * 4;
    f32x4 v = *(const f32x4*)(src + (long)(r0 + r) * X + x0 + xq);
    t[r][xq + 0] = v[0]; t[r][xq + 1] = v[1]; t[r][xq + 2] = v[2]; t[r][xq + 3] = v[3];
  }
  __syncthreads();
#pragma unroll
  for (int rep = 0; rep < 2; ++rep) {
    int u = tid + rep * 256;
    int s = u >> 3, cq = (u & 7) * 8;
    u16x8 o;
#pragma unroll
    for (int j = 0; j < 8; ++j) o[j] = f2bf(t[cq + j][s]);
    *(u16x8*)(dst + (long)(x0 + s) * R + r0 + cq) = o;
  }
}

// ---------------- GEMM: C[m][n] = sum_k A[m][k] * B[n][k]  (both bf16 K-contig) ----------------
// MODE 0: bf16 out, bias[n]
// MODE 1: bf16 out, bias[m]
// MODE 2: f32 out, * scale
// MODE 3: f32 out, plain
// MODE 4: f32 out, bias[m]; B staged from f32 src with LayerNorm+affine+ReLU (lnw/lnb bf16, stats per batch)
template <int MODE>
__global__ __launch_bounds__(256) void gemm128(const u16* __restrict__ Ag,
                                               const void* __restrict__ Bg,
                                               void* __restrict__ Cg,
                                               int K, int ldc,
                                               long aB, long bB, long cB,
                                               const float* __restrict__ bias, float scale,
                                               const u16* __restrict__ lnw,
                                               const u16* __restrict__ lnb,
                                               const float* __restrict__ stats) {
  const int tid = threadIdx.x;
  const int z = blockIdx.z;
  const u16* A = Ag + (long)z * aB;
  const int r0 = blockIdx.y * 128, c0 = blockIdx.x * 128;

  __shared__ __align__(16) u16 At[128 * 40];
  __shared__ __align__(16) u16 Bt[128 * 40];

  f32x4 acc[4][4];
#pragma unroll
  for (int i = 0; i < 4; ++i)
#pragma unroll
    for (int j = 0; j < 4; ++j) acc[i][j] = (f32x4)0.f;

  float mu = 0.f, rstd = 0.f;
  const float* Bf = nullptr;
  const u16* Bh = nullptr;
  if constexpr (MODE == 4) {
    Bf = (const float*)Bg + (long)z * bB;
    mu = stats[z * 2 + 0];
    rstd = stats[z * 2 + 1];
  } else {
    Bh = (const u16*)Bg + (long)z * bB;
  }

  const int lane = tid & 63, wid = tid >> 6;
  const int wm = (wid >> 1) * 64, wn = (wid & 1) * 64;
  const int lrow = lane & 15, kof = (lane >> 4) * 8;

  for (int kt = 0; kt < K; kt += 32) {
    // stage A tile (128 x 32 bf16)
#pragma unroll
    for (int rep = 0; rep < 2; ++rep) {
      int u = tid + rep * 256;
      int row = u >> 2, q = (u & 3) * 8;
      *(u32x4*)&At[row * 40 + q] = *(const u32x4*)(A + (long)(r0 + row) * K + kt + q);
    }
    // stage B tile
    if constexpr (MODE == 4) {
#pragma unroll
      for (int rep = 0; rep < 4; ++rep) {
        int u = tid + rep * 256;
        int row = u >> 3, q = (u & 7) * 4;
        long off = (long)(c0 + row) * K + kt + q;
        f32x4 x = *(const f32x4*)(Bf + off);
        u16x4 w4 = *(const u16x4*)(lnw + off);
        u16x4 b4 = *(const u16x4*)(lnb + off);
        u16x4 o;
#pragma unroll
        for (int e = 0; e < 4; ++e) {
          float y = (x[e] - mu) * rstd * bf2f(w4[e]) + bf2f(b4[e]);
          y = fmaxf(y, 0.f);
          o[e] = f2bf(y);
        }
        *(u16x4*)&Bt[row * 40 + q] = o;
      }
    } else {
#pragma unroll
      for (int rep = 0; rep < 2; ++rep) {
        int u = tid + rep * 256;
        int row = u >> 2, q = (u & 3) * 8;
        *(u32x4*)&Bt[row * 40 + q] = *(const u32x4*)(Bh + (long)(c0 + row) * K + kt + q);
      }
    }
    __syncthreads();
    s16x8 af[4], bfr[4];
#pragma unroll
    for (int i = 0; i < 4; ++i) af[i] = *(const s16x8*)&At[(wm + i * 16 + lrow) * 40 + kof];
#pragma unroll
    for (int j = 0; j < 4; ++j) bfr[j] = *(const s16x8*)&Bt[(wn + j * 16 + lrow) * 40 + kof];
#pragma unroll
    for (int i = 0; i < 4; ++i)
#pragma unroll
      for (int j = 0; j < 4; ++j)
        acc[i][j] = __builtin_amdgcn_mfma_f32_16x16x32_bf16(af[i], bfr[j], acc[i][j], 0, 0, 0);
    __syncthreads();
  }

  // epilogue: D[row][col], row = (lane>>4)*4 + r, col = lane&15 (m89-verified layout)
  const int ri = (lane >> 4) * 4, ci = lane & 15;
#pragma unroll
  for (int i = 0; i < 4; ++i) {
#pragma unroll
    for (int j = 0; j < 4; ++j) {
#pragma unroll
      for (int r = 0; r < 4; ++r) {
        int m = r0 + wm + i * 16 + ri + r;
        int n = c0 + wn + j * 16 + ci;
        float v = acc[i][j][r];
        long idx = (long)z * cB + (long)m * ldc + n;
        if constexpr (MODE == 0) {
          ((u16*)Cg)[idx] = f2bf(v + bias[n]);
        } else if constexpr (MODE == 1) {
          ((u16*)Cg)[idx] = f2bf(v + bias[m]);
        } else if constexpr (MODE == 2) {
          ((float*)Cg)[idx] = v * scale;
        } else if constexpr (MODE == 3) {
          ((float*)Cg)[idx] = v;
        } else {
          ((float*)Cg)[idx] = v + bias[m];
        }
      }
    }
  }
}

// ---------------- row softmax over 2048 f32 -> bf16 ----------------
__global__ __launch_bounds__(256) void softmax2048(const float* __restrict__ S,
                                                   u16* __restrict__ P) {
  long row = blockIdx.x;
  const float* src = S + row * 2048;
  u16* dst = P + row * 2048;
  int tid = threadIdx.x;
  f32x4 v0 = *(const f32x4*)(src + tid * 8);
  f32x4 v1 = *(const f32x4*)(src + tid * 8 + 4);
  float m = fmaxf(fmaxf(fmaxf(v0[0], v0[1]), fmaxf(v0[2], v0[3])),
                  fmaxf(fmaxf(v1[0], v1[1]), fmaxf(v1[2], v1[3])));
  __shared__ float red[4], red2[4];
#pragma unroll
  for (int off = 32; off; off >>= 1) m = fmaxf(m, __shfl_xor(m, off));
  if ((tid & 63) == 0) red[tid >> 6] = m;
  __syncthreads();
  m = fmaxf(fmaxf(red[0], red[1]), fmaxf(red[2], red[3]));
  float e[8];
  float s = 0.f;
#pragma unroll
  for (int j = 0; j < 4; ++j) { e[j] = __expf(v0[j] - m); s += e[j]; }
#pragma unroll
  for (int j = 0; j < 4; ++j) { e[4 + j] = __expf(v1[j] - m); s += e[4 + j]; }
#pragma unroll
  for (int off = 32; off; off >>= 1) s += __shfl_xor(s, off);
  if ((tid & 63) == 0) red2[tid >> 6] = s;
  __syncthreads();
  s = red2[0] + red2[1] + red2[2] + red2[3];
  float inv = 1.f / s;
  u16x8 o;
#pragma unroll
  for (int j = 0; j < 8; ++j) o[j] = f2bf(e[j] * inv);
  *(u16x8*)(dst + tid * 8) = o;
}

// ---------------- LayerNorm stats (2-stage) ----------------
__global__ __launch_bounds__(256) void ln_part(const float* __restrict__ outT,
                                               float* __restrict__ part) {
  int bx = blockIdx.x;
  int b = bx >> 3, sl = bx & 7;
  const float* src = outT + (long)b * 262144 + sl * 32768;
  int tid = threadIdx.x;
  float s = 0.f, q = 0.f;
#pragma unroll
  for (int it = 0; it < 32; ++it) {
    f32x4 v = *(const f32x4*)(src + (it * 256 + tid) * 4);
    s += v[0] + v[1] + v[2] + v[3];
    q += v[0] * v[0] + v[1] * v[1] + v[2] * v[2] + v[3] * v[3];
  }
#pragma unroll
  for (int off = 32; off; off >>= 1) { s += __shfl_xor(s, off); q += __shfl_xor(q, off); }
  __shared__ float rs[4], rq[4];
  if ((tid & 63) == 0) { rs[tid >> 6] = s; rq[tid >> 6] = q; }
  __syncthreads();
  if (tid == 0) {
    part[bx * 2 + 0] = rs[0] + rs[1] + rs[2] + rs[3];
    part[bx * 2 + 1] = rq[0] + rq[1] + rq[2] + rq[3];
  }
}

__global__ void ln_final(const float* __restrict__ part, float* __restrict__ stats) {
  int b = blockIdx.x;
  int lane = threadIdx.x;
  float s = 0.f, q = 0.f;
  if (lane < 8) {
    s = part[(b * 8 + lane) * 2 + 0];
    q = part[(b * 8 + lane) * 2 + 1];
  }
#pragma unroll
  for (int off = 4; off; off >>= 1) { s += __shfl_xor(s, off); q += __shfl_xor(q, off); }
  if (lane == 0) {
    const float M = 262144.f;
    float mu = s / M;
    float var = q / M - mu * mu;
    stats[b * 2 + 0] = mu;
    stats[b * 2 + 1] = rsqrtf(var + 1e-5f);
  }
}

extern "C" void kernel_launch(void* const* d_in, const int* in_sizes, int n_in,
                              void* d_out, int out_size, void* d_ws, size_t ws_size,
                              hipStream_t stream) {
  const float* st = (const float*)d_in[0];
  const float* lt = (const float*)d_in[1];
  const float* w_st = (const float*)d_in[2];
  const float* b_st = (const float*)d_in[3];
  const float* w_lt = (const float*)d_in[4];
  const float* b_lt = (const float*)d_in[5];
  const float* w_g = (const float*)d_in[6];
  const float* b_g = (const float*)d_in[7];
  const float* ln_w = (const float*)d_in[8];
  const float* ln_b = (const float*)d_in[9];
  const float* w_out = (const float*)d_in[10];
  const float* b_out = (const float*)d_in[11];
  float* out = (float*)d_out;
  (void)in_sizes; (void)n_in; (void)out_size; (void)ws_size;

  char* ws = (char*)d_ws;
  size_t off = 0;
  auto alloc = [&](size_t bytes) -> void* {
    void* p = ws + off;
    off += (bytes + 255) & ~(size_t)255;
    return p;
  };
  u16* wstB = (u16*)alloc((size_t)512 * 2048 * 2);
  u16* wltB = (u16*)alloc((size_t)512 * 2048 * 2);
  u16* wgB = (u16*)alloc((size_t)512 * 2048 * 2);
  u16* woutB = (u16*)alloc((size_t)2048 * 512 * 2);
  u16* lnwT = (u16*)alloc((size_t)512 * 512 * 2);
  u16* lnbT = (u16*)alloc((size_t)512 * 512 * 2);
  float* part = (float*)alloc(256 * 2 * 4);
  float* stats = (float*)alloc(32 * 2 * 4);
  u16* stT = (u16*)alloc((size_t)32 * 512 * 2048 * 2);    // reused later for p (bf16)
  u16* thetaT = (u16*)alloc((size_t)32 * 512 * 512 * 2);
  u16* phiT = (u16*)alloc((size_t)32 * 2048 * 512 * 2);
  u16* gB = (u16*)alloc((size_t)32 * 512 * 2048 * 2);
  u16* ltT = (u16*)alloc((size_t)32 * 2048 * 2048 * 2);   // reused: scores f32 (134MB) then outT
  float* scores = (float*)ltT;
  u16* p = stT;
  float* outT = (float*)((char*)ltT + (size_t)32 * 512 * 2048 * 4);

  const float inv_sqrt_lat = 0.044194173824159216f;

  // weight converts (each 1048576 elems = 262144 float4)
  cvt_f32_bf16<<<dim3(1024), dim3(256), 0, stream>>>(w_st, wstB, 262144);
  cvt_f32_bf16<<<dim3(1024), dim3(256), 0, stream>>>(w_lt, wltB, 262144);
  cvt_f32_bf16<<<dim3(1024), dim3(256), 0, stream>>>(w_g, wgB, 262144);
  cvt_f32_bf16<<<dim3(1024), dim3(256), 0, stream>>>(w_out, woutB, 262144);

  // ln transposes: (512,512) f32 -> (512,512) bf16 transposed
  transpose_cvt<<<dim3(8, 8, 1), 256, 0, stream>>>(ln_w, lnwT, 512, 512, 0, 0);
  transpose_cvt<<<dim3(8, 8, 1), 256, 0, stream>>>(ln_b, lnbT, 512, 512, 0, 0);

  // stT (N,512,2048) <- st (N,2048,512)
  transpose_cvt<<<dim3(8, 32, 32), 256, 0, stream>>>(st, stT, 2048, 512,
                                                     (long)2048 * 512, (long)512 * 2048);
  // thetaT (N,S,LAT) = stT x w_st^T + b_st[n]
  gemm128<0><<<dim3(4, 4, 32), 256, 0, stream>>>(stT, wstB, thetaT, 2048, 512,
                                                 (long)512 * 2048, 0L, (long)512 * 512,
                                                 b_st, 1.f, nullptr, nullptr, nullptr);
  // ltT (N,2048,2048) <- lt (N,2048,2048)
  transpose_cvt<<<dim3(32, 32, 32), 256, 0, stream>>>(lt, ltT, 2048, 2048,
                                                      (long)2048 * 2048, (long)2048 * 2048);
  // phiT (N,L,LAT) = ltT x w_lt^T + b_lt[n]
  gemm128<0><<<dim3(4, 16, 32), 256, 0, stream>>>(ltT, wltB, phiT, 2048, 512,
                                                  (long)2048 * 2048, 0L, (long)2048 * 512,
                                                  b_lt, 1.f, nullptr, nullptr, nullptr);
  // g (N,LAT,L) = w_g x lt + b_g[m]
  gemm128<1><<<dim3(16, 4, 32), 256, 0, stream>>>(wgB, ltT, gB, 2048, 2048,
                                                  0L, (long)2048 * 2048, (long)512 * 2048,
                                                  b_g, 1.f, nullptr, nullptr, nullptr);
  // scores (N,S,L) f32 = thetaT x phiT^T * 1/sqrt(LAT)   (into ltT region)
  gemm128<2><<<dim3(16, 4, 32), 256, 0, stream>>>(thetaT, phiT, scores, 512, 2048,
                                                  (long)512 * 512, (long)2048 * 512,
                                                  (long)512 * 2048,
                                                  nullptr, inv_sqrt_lat, nullptr, nullptr, nullptr);
  // softmax rows -> p bf16 (into stT region)
  softmax2048<<<dim3(32 * 512), 256, 0, stream>>>(scores, p);
  // outT (N,S,LAT) f32 = p x g^T
  gemm128<3><<<dim3(4, 4, 32), 256, 0, stream>>>(p, gB, outT, 2048, 512,
                                                 (long)512 * 2048, (long)512 * 2048,
                                                 (long)512 * 512,
                                                 nullptr, 1.f, nullptr, nullptr, nullptr);
  // LN stats
  ln_part<<<dim3(256), 256, 0, stream>>>(outT, part);
  ln_final<<<dim3(32), 64, 0, stream>>>(part, stats);
  // final: out (N,C_ST,S) f32 = w_out x relu(LN(outT)) + b_out[m]
  gemm128<4><<<dim3(4, 16, 32), 256, 0, stream>>>(woutB, outT, out, 512, 512,
                                                  0L, (long)512 * 512, (long)2048 * 512,
                                                  b_out, 1.f, lnwT, lnbT, stats);
}